// Round 2
// 694.477 us; speedup vs baseline: 1.0246x; 1.0246x over previous
//
#include <hip/hip_runtime.h>

// Fixed problem dims from setup_inputs(): b=16, L=256, h=256, eh=64, M=N=128.
// Output layout (flat float32, element offsets):
//   X1      @ 0           (16,256,256)   = 1,048,576
//   X2      @ 1,048,576   (16,256,256)
//   E1      @ 2,097,152   (16,256,256,64)= 67,108,864
//   E2      @ 69,206,016  (16,256,256,64)
//   A1      @ 136,314,880 (16,256,256)
//   A2      @ 137,363,456 (16,256,256)
//   mask1   @ 138,412,032 (16,256,256)
//   mask2   @ 139,460,608 (16,256,256)
//   w1      @ 140,509,184 (16,256,1)     = 4,096
//   w2      @ 140,513,280 (16,256,1)
//   mask_out@ 140,517,376 (16,256,256)
// total 141,565,952 elements = 566 MB mandatory writes.

#define OFF_X1   0
#define OFF_X2   1048576
#define OFF_E1   2097152
#define OFF_E2   69206016
#define OFF_A1   136314880
#define OFF_A2   137363456
#define OFF_M1   138412032
#define OFF_M2   139460608
#define OFF_W1   140509184
#define OFF_MO   140517376

#define OFF_E1_V4 (OFF_E1 / 4)   //   524,288 float4
#define OFF_E2_V4 (OFF_E2 / 4)   // 17,301,504 float4

// clang ext-vector type: __builtin_nontemporal_store accepts this (HIP's
// float4 struct is rejected by the builtin's type check).
typedef float f32x4 __attribute__((ext_vector_type(4)));

// Single fused kernel.
// Grid: 65,536 blocks x 256 threads. Each thread writes one float4 of E1 and
// one float4 of E2 (16,777,216 float4 each). Blocks 0..4095 additionally
// produce X1/X2/A1/A2/mask1/mask2/mask_out/w1/w2 (1,048,576 scalar threads).
//
// Key decode choice: i and p are derived from blockIdx.x ONLY, so they are
// block-uniform -> mol_lens loads become scalar (s_load) and the block
// predicates become SALU, not per-lane VALU + per-lane global loads.
__global__ __launch_bounds__(256) void fused_kernel(
    const f32x4* __restrict__ E,        // (16,256,256,16) float4
    const float* __restrict__ X,        // (16,256,256)
    const float* __restrict__ A,        // (16,256,256)
    const int*   __restrict__ mask,     // (16,256,256) bool as 4-byte elems
    const int*   __restrict__ mol_lens, // (16,2)
    float*       __restrict__ out)
{
    const int bb  = blockIdx.x;
    const int tid = threadIdx.x;

    // ---- E-part decode: t = bb*256+tid over (i:16, p:256, q:256, c:16) ----
    const int i = bb >> 12;                      // block-uniform
    const int p = (bb >> 4) & 255;               // block-uniform
    const int q = ((bb & 15) << 4) | (tid >> 4); // per-lane (16 values/block)
    const int c = tid & 15;
    const int t = bb * 256 + tid;                // 0 .. 16,777,215

    const int l0 = mol_lens[i * 2];              // scalar loads
    const int l1 = mol_lens[i * 2 + 1];

    f32x4* outv4 = (f32x4*)out;

    // ---- E1: l=l0, base=0 ----
    {
        const bool fp = p < l0, sp = !fp && (p < 2 * l0);   // uniform
        const bool fq = q < l0, sq = !fq && (q < 2 * l0);   // per-lane
        f32x4 v = (f32x4)(0.f, 0.f, 0.f, 0.f);
        if ((fp && fq) || (sp && sq)) {
            const int ip = fp ? p : p - l0;   // < l0 <= 128, no clamp needed
            const int iq = fq ? q : q - l0;
            v = E[((i * 256 + ip) * 256 + iq) * 16 + c];
        }
        __builtin_nontemporal_store(v, &outv4[OFF_E1_V4 + t]);
    }

    // ---- E2: l=l1, base=l0 ----
    {
        const bool fp = p < l1, sp = !fp && (p < 2 * l1);
        const bool fq = q < l1, sq = !fq && (q < 2 * l1);
        f32x4 v = (f32x4)(0.f, 0.f, 0.f, 0.f);
        if ((fp && fq) || (sp && sq)) {
            int ip = l0 + (fp ? p : p - l1); if (ip > 255) ip = 255;
            int iq = l0 + (fq ? q : q - l1); if (iq > 255) iq = 255;
            v = E[((i * 256 + ip) * 256 + iq) * 16 + c];
        }
        __builtin_nontemporal_store(v, &outv4[OFF_E2_V4 + t]);
    }

    // ---- small part: one scalar thread per (is, ps, qs) over (16,256,256) ----
    if (bb < 4096) {
        const int ts = t;            // 0 .. 1,048,575
        const int qs = tid;          // per-lane
        const int ps = bb & 255;     // block-uniform
        const int is = bb >> 8;      // block-uniform

        const int sl0 = mol_lens[is * 2];
        const int sl1 = mol_lens[is * 2 + 1];

        // X1
        const bool v1  = ps < 2 * sl0;
        const int  s1p = (ps < sl0) ? ps : ps - sl0;
        __builtin_nontemporal_store(
            v1 ? X[(is * 256 + s1p) * 256 + qs] : 0.f, &out[OFF_X1 + ts]);

        // X2
        const bool v2  = ps < 2 * sl1;
        const int  s2p = (ps < sl1) ? ps : ps - sl1;
        __builtin_nontemporal_store(
            v2 ? X[(is * 256 + s2p) * 256 + qs] : 0.f, &out[OFF_X2 + ts]);

        // A1 / mask1
        const bool f1p = ps < sl0, s1pb = (!f1p) && v1;
        const bool f1q = qs < sl0, s1qb = (!f1q) && (qs < 2 * sl0);
        const int  s1q = f1q ? qs : qs - sl0;
        const bool blk1 = (f1p && f1q) || (s1pb && s1qb);
        __builtin_nontemporal_store(
            blk1 ? A[(is * 256 + s1p) * 256 + s1q] : 0.f, &out[OFF_A1 + ts]);
        __builtin_nontemporal_store(
            ((f1p && s1qb) || (s1pb && f1q)) ? 0.f : 1.f, &out[OFF_M1 + ts]);

        // A2 / mask2
        const bool f2p = ps < sl1, s2pb = (!f2p) && v2;
        const bool f2q = qs < sl1, s2qb = (!f2q) && (qs < 2 * sl1);
        int e2p = sl0 + (f2p ? ps : ps - sl1); if (e2p > 255) e2p = 255;
        int e2q = sl0 + (f2q ? qs : qs - sl1); if (e2q > 255) e2q = 255;
        const bool blk2 = (f2p && f2q) || (s2pb && s2qb);
        __builtin_nontemporal_store(
            blk2 ? A[(is * 256 + e2p) * 256 + e2q] : 0.f, &out[OFF_A2 + ts]);
        __builtin_nontemporal_store(
            ((f2p && s2qb) || (s2pb && f2q)) ? 0.f : 1.f, &out[OFF_M2 + ts]);

        // mask_out
        const bool leftp = ps < sl0, leftq = qs < sl0;
        const int  lsum  = sl0 + sl1;
        const bool middp = (!leftp) && (ps < lsum);
        const bool middq = (!leftq) && (qs < lsum);
        const bool ct = (leftp && leftq) || ((!leftp) && (!leftq));
        const bool cf = (leftp && middq) || (middp && leftq);
        float mv;
        if (ct)      mv = 1.f;
        else if (cf) mv = 0.f;
        else         mv = (mask[ts] != 0) ? 1.f : 0.f;
        __builtin_nontemporal_store(mv, &out[OFF_MO + ts]);

        // w1/w2 zeros: first 8192 scalar threads (blocks 0..31)
        if (ts < 8192)
            __builtin_nontemporal_store(0.f, &out[OFF_W1 + ts]);
    }
}

extern "C" void kernel_launch(void* const* d_in, const int* in_sizes, int n_in,
                              void* d_out, int out_size, void* d_ws, size_t ws_size,
                              hipStream_t stream) {
    const float* X        = (const float*)d_in[0];
    const float* E        = (const float*)d_in[1];
    const float* A        = (const float*)d_in[2];
    // d_in[3] = w (unused: w1/w2 are zeros)
    const int*   mask     = (const int*)d_in[4];
    const int*   mol_lens = (const int*)d_in[5];
    // d_in[6]=M, d_in[7]=N — compile-time known (128)

    float* out = (float*)d_out;

    fused_kernel<<<65536, 256, 0, stream>>>(
        (const f32x4*)E, X, A, mask, mol_lens, out);
}